// Round 5
// baseline (523.390 us; speedup 1.0000x reference)
//
#include <hip/hip_runtime.h>
#include <stdint.h>

#define L2E 1.44269504088896f

static __device__ __forceinline__ float wsum(float v) {
    #pragma unroll
    for (int m = 1; m < 64; m <<= 1) v += __shfl_xor(v, m, 64);
    return v;
}
static __device__ __forceinline__ float sigm(float x) {
    return 1.0f / (1.0f + __builtin_amdgcn_exp2f(-x * L2E));
}
static __device__ __forceinline__ float tanh_(float x) {
    const float ax = fabsf(x);
    const float t = __builtin_amdgcn_exp2f(-2.0f * ax * L2E);
    const float r = (1.0f - t) / (1.0f + t);
    return (x < 0.f) ? -r : r;
}

// ---------------------------------------------------------------------------
// init: fused weight transpose (wihT/whhT/WkT), cnt zero, slot broadcast,
// and iter-0 gkq/aux production. grid 112 x 256 (28672 thr = transpose elems).
// ---------------------------------------------------------------------------
__global__ __launch_bounds__(256) void init_kernel(
    const float* __restrict__ s0,
    const float* __restrict__ lsg, const float* __restrict__ lsb,
    const float* __restrict__ Wq,  const float* __restrict__ Wk,
    const float* __restrict__ lig, const float* __restrict__ lib,
    const float* __restrict__ wih, const float* __restrict__ whh,
    float* __restrict__ slots, float* __restrict__ gkq, float* __restrict__ aux,
    float* __restrict__ wihT, float* __restrict__ whhT, float* __restrict__ WkT,
    int* __restrict__ cnt)
{
    __shared__ float wkT[4096];
    __shared__ float scr[4][64];
    const int tid = threadIdx.x, lane = tid & 63, wv = tid >> 6;
    const int idx = blockIdx.x * 256 + tid;

    // transposes (one element per thread, exact cover)
    if (idx < 12288) {
        const int i = idx / 192, j = idx - i * 192;
        wihT[idx] = wih[j * 64 + i];
    } else if (idx < 24576) {
        const int o = idx - 12288;
        const int i = o / 192, j = o - i * 192;
        whhT[o] = whh[j * 64 + i];
    } else {
        const int o = idx - 24576;
        const int p = o >> 6, d = o & 63;
        WkT[o] = Wk[d * 64 + p];
    }
    if (idx < 64) cnt[idx] = 0;

    const int r = blockIdx.x * 4 + wv;          // 0..447
    const int s = r % 7;
    #pragma unroll
    for (int i = tid; i < 4096; i += 256) {
        const int d = i >> 6, p = i & 63;
        wkT[p * 64 + d] = Wk[i];
    }
    const float h = s0[s * 64 + lane];
    slots[r * 64 + lane] = h;
    __syncthreads();

    // LN(slot) -> q -> kq -> gkq/aux
    const float mean = wsum(h) * (1.0f / 64.0f);
    const float d = h - mean;
    const float var = wsum(d * d) * (1.0f / 64.0f);
    const float rs = rsqrtf(var + 1e-5f);
    const float sn = d * rs * lsg[lane] + lsb[lane];
    scr[wv][lane] = sn;
    __syncthreads();
    float q = 0.f;
    #pragma unroll 8
    for (int i = 0; i < 64; ++i) q = fmaf(scr[wv][i], Wq[i * 64 + lane], q);
    q *= 0.125f;
    __syncthreads();
    scr[wv][lane] = q;
    __syncthreads();
    float kq = 0.f;
    #pragma unroll 8
    for (int p = 0; p < 64; ++p) kq = fmaf(wkT[p * 64 + lane], scr[wv][p], kq);
    const float bk = wsum(lib[lane] * kq);
    const float gk = lig[lane] * kq;
    const float g1 = wsum(gk);
    gkq[r * 64 + lane] = gk;
    if (lane == 0) { aux[r * 2] = g1; aux[r * 2 + 1] = bk; }
}

// ---------------------------------------------------------------------------
// attn pass helpers
// ---------------------------------------------------------------------------
static __device__ __forceinline__ void stage_store(float* xw, const float4* R, int lane)
{
    #pragma unroll
    for (int st = 0; st < 8; ++st) {
        const int row = st * 4 + (lane >> 4);
        const int dim = (lane & 15) * 4;
        float* d = xw + row * 65 + dim;
        d[0] = R[st].x; d[1] = R[st].y; d[2] = R[st].z; d[3] = R[st].w;
    }
}

static __device__ __forceinline__ void do_pass(
    float* __restrict__ xw, float* __restrict__ wshw,
    const float* __restrict__ gkql, const float* __restrict__ auxl,
    int q5, int h, float* Yr, float* cacc)
{
    // ---- Phase A: row = q5, dims h*32..h*32+31 ----
    float xf[32];
    float sum = 0.f, ss = 0.f;
    const float* xr = xw + q5 * 65 + h * 32;
    #pragma unroll
    for (int c = 0; c < 32; ++c) {
        xf[c] = xr[c];
        sum += xf[c];
        ss = fmaf(xf[c], xf[c], ss);
    }
    float acc[7];
    #pragma unroll
    for (int s = 0; s < 7; ++s) {
        float a = 0.f;
        const float* gk = &gkql[s * 64 + h * 32];
        #pragma unroll
        for (int c = 0; c < 32; ++c) a = fmaf(xf[c], gk[c], a);
        acc[s] = a;
    }
    sum += __shfl_xor(sum, 32, 64);
    ss  += __shfl_xor(ss, 32, 64);
    #pragma unroll
    for (int s = 0; s < 7; ++s) acc[s] += __shfl_xor(acc[s], 32, 64);

    const float m   = sum * (1.0f / 64.0f);
    const float var = ss * (1.0f / 64.0f) - m * m;
    const float rs  = rsqrtf(var + 1e-5f);
    const float rsm = rs * m;
    float t[7];
    #pragma unroll
    for (int s = 0; s < 7; ++s)
        t[s] = fmaf(rs, acc[s], fmaf(-rsm, auxl[2 * s], auxl[2 * s + 1]));
    float mx = t[0];
    #pragma unroll
    for (int s = 1; s < 7; ++s) mx = fmaxf(mx, t[s]);
    float e[7], se = 0.f;
    #pragma unroll
    for (int s = 0; s < 7; ++s) {
        e[s] = __builtin_amdgcn_exp2f((t[s] - mx) * L2E);
        se += e[s];
    }
    const float inv = 1.0f / se;
    #pragma unroll
    for (int s = 0; s < 7; ++s) {
        const float w = fmaf(e[s], inv, 1e-8f);
        cacc[s] += w;                           // both halves: x2, fixed later
        if (h == 0) wshw[q5 * 8 + s] = w * rs;
    }
    if (h == 0) wshw[q5 * 8 + 7] = 0.f;
    __builtin_amdgcn_wave_barrier();

    // ---- Phase B: rows 2*r2+h, dims q5*2, q5*2+1 ----
    #pragma unroll 4
    for (int r2 = 0; r2 < 16; ++r2) {
        const int rr = r2 * 2 + h;
        const float4 p0 = *(const float4*)&wshw[rr * 8];
        const float4 p1 = *(const float4*)&wshw[rr * 8 + 4];
        const float v0 = xw[rr * 65 + q5 * 2];
        const float v1 = xw[rr * 65 + q5 * 2 + 1];
        const float ps[7] = {p0.x, p0.y, p0.z, p0.w, p1.x, p1.y, p1.z};
        #pragma unroll
        for (int s = 0; s < 7; ++s) {
            Yr[2 * s]     = fmaf(ps[s], v0, Yr[2 * s]);
            Yr[2 * s + 1] = fmaf(ps[s], v1, Yr[2 * s + 1]);
        }
    }
}

// ---------------------------------------------------------------------------
// attn (per iteration), fused with slot update: each block computes its
// (b,chunk) Ypart slice; the last-arriving block per b (atomic counter)
// performs the GRU/MLP update for all 7 slots of b and writes gkq/aux for
// the next launch (or d_out on the last iteration). grid B*16 = 1024 x 256.
// ---------------------------------------------------------------------------
__global__ __launch_bounds__(256, 4) void attn_kernel(
    const float* __restrict__ x,
    float* __restrict__ gkq, float* __restrict__ aux,
    float* __restrict__ Ypart, int* __restrict__ cnt,
    float* __restrict__ slots,
    const float* __restrict__ Wv,
    const float* __restrict__ wihT, const float* __restrict__ whhT,
    const float* __restrict__ bih,  const float* __restrict__ bhh,
    const float* __restrict__ w1,   const float* __restrict__ b1,
    const float* __restrict__ w2,   const float* __restrict__ b2,
    const float* __restrict__ lsg,  const float* __restrict__ lsb,
    const float* __restrict__ Wq,   const float* __restrict__ WkT,
    const float* __restrict__ lig,  const float* __restrict__ lib,
    float* __restrict__ out, int last)
{
    __shared__ float xsh[4][2080];              // 32 rows x 65 (pad) per wave
    __shared__ float wsh[4][256];               // 32 x 8 per wave
    __shared__ float gkql[448];
    __shared__ float auxl[14];
    __shared__ int winflag;
    const int tid = threadIdx.x, lane = tid & 63, wv = tid >> 6;
    const int b = blockIdx.x >> 4, chunk = blockIdx.x & 15;

    gkql[tid] = gkq[b * 448 + tid];
    if (tid < 192) gkql[tid + 256] = gkq[b * 448 + tid + 256];
    if (tid < 14) auxl[tid] = aux[b * 14 + tid];
    __syncthreads();

    const int q5 = lane & 31, h = lane >> 5;
    float Yr[14];
    #pragma unroll
    for (int i = 0; i < 14; ++i) Yr[i] = 0.f;
    float cacc[7] = {0.f, 0.f, 0.f, 0.f, 0.f, 0.f, 0.f};

    float* xw = &xsh[wv][0];
    float* wshw = &wsh[wv][0];
    const float* tbase = x + (((long)b * 4096) + chunk * 256 + wv * 64) * 64;

    // pass 0 stage + pass 1 prefetch (loads fly during pass-0 compute)
    {
        const float4* srcA = (const float4*)tbase;
        float4 Ra[8];
        #pragma unroll
        for (int st = 0; st < 8; ++st) Ra[st] = srcA[st * 64 + lane];
        stage_store(xw, Ra, lane);
    }
    float4 Rb[8];
    {
        const float4* srcB = (const float4*)(tbase + 2048);
        #pragma unroll
        for (int st = 0; st < 8; ++st) Rb[st] = srcB[st * 64 + lane];
    }
    do_pass(xw, wshw, gkql, auxl, q5, h, Yr, cacc);
    __builtin_amdgcn_wave_barrier();            // pass-0 LDS reads precede overwrite
    stage_store(xw, Rb, lane);
    do_pass(xw, wshw, gkql, auxl, q5, h, Yr, cacc);

    // ---- wave reduce; ybuf aliased onto own wave's xsh (dead now) ----
    #pragma unroll
    for (int i = 0; i < 14; ++i) Yr[i] += __shfl_xor(Yr[i], 32, 64);
    __builtin_amdgcn_wave_barrier();
    if (h == 0) {
        #pragma unroll
        for (int s = 0; s < 7; ++s) {
            xw[s * 64 + q5 * 2]     = Yr[2 * s];
            xw[s * 64 + q5 * 2 + 1] = Yr[2 * s + 1];
        }
    }
    #pragma unroll
    for (int s = 0; s < 7; ++s) {
        const float Cs = wsum(cacc[s]) * 0.5f;  // each row counted twice
        if (lane == 0) xw[448 + s] = Cs;
    }
    __syncthreads();
    for (int i = tid; i < 455; i += 256)
        Ypart[((long)b * 16 + chunk) * 456 + i] =
            xsh[0][i] + xsh[1][i] + xsh[2][i] + xsh[3][i];

    // ---- last block per b claims the slot update ----
    __threadfence();
    if (tid == 0) winflag = (atomicAdd(&cnt[b], 1) == 15) ? 1 : 0;
    __syncthreads();
    if (!winflag) return;
    __threadfence();
    if (tid == 0) cnt[b] = 0;                   // rearm for next launch

    // ---- update tail: wave wv handles slots {wv, wv+4}; wave-local sync only
    const float* Yb = Ypart + (long)b * 16 * 456;
    float* sw = &xsh[wv][0];                    // per-wave scratch
    #pragma unroll 1
    for (int si = 0; si < 2; ++si) {
        const int s = wv + si * 4;
        if (s >= 7) break;
        const int r = b * 7 + s;

        float Yd = 0.f, C = 0.f;
        #pragma unroll
        for (int c = 0; c < 16; ++c) {
            Yd += Yb[c * 456 + s * 64 + lane];
            C  += Yb[c * 456 + 448 + s];
        }
        const float Z = wsum(Yd) * (1.0f / 64.0f);
        const float aoc = (lig[lane] * (Yd - Z) + lib[lane] * C) / C;
        sw[lane] = aoc;
        __builtin_amdgcn_wave_barrier();
        float u = 0.f;
        #pragma unroll 8
        for (int i = 0; i < 64; ++i) u = fmaf(sw[i], Wv[i * 64 + lane], u);
        const float hv = slots[r * 64 + lane];
        __builtin_amdgcn_wave_barrier();
        sw[64 + lane] = u; sw[128 + lane] = hv;
        __builtin_amdgcn_wave_barrier();

        float gi[3], gh[3];
        #pragma unroll
        for (int g = 0; g < 3; ++g) {
            const int j = g * 64 + lane;
            float a1 = bih[j], a2 = bhh[j];
            #pragma unroll 8
            for (int i = 0; i < 64; ++i) {
                a1 = fmaf(sw[64 + i],  wihT[i * 192 + j], a1);
                a2 = fmaf(sw[128 + i], whhT[i * 192 + j], a2);
            }
            gi[g] = a1; gh[g] = a2;
        }
        const float rr = sigm(gi[0] + gh[0]);
        const float zz = sigm(gi[1] + gh[1]);
        const float nn = tanh_(gi[2] + rr * gh[2]);
        const float hn = (1.f - zz) * nn + zz * hv;
        sw[192 + lane] = hn;
        __builtin_amdgcn_wave_barrier();

        float m0 = b1[lane], m1 = b1[64 + lane];
        #pragma unroll 8
        for (int i = 0; i < 64; ++i) {
            const float hni = sw[192 + i];
            m0 = fmaf(hni, w1[i * 128 + lane], m0);
            m1 = fmaf(hni, w1[i * 128 + 64 + lane], m1);
        }
        m0 = fmaxf(m0, 0.f); m1 = fmaxf(m1, 0.f);
        sw[256 + lane] = m0; sw[320 + lane] = m1;
        __builtin_amdgcn_wave_barrier();
        float o = b2[lane];
        #pragma unroll 8
        for (int t = 0; t < 128; ++t) o = fmaf(sw[256 + t], w2[t * 64 + lane], o);
        const float snv = hn + o;
        slots[r * 64 + lane] = snv;

        if (last) {
            out[r * 64 + lane] = snv;
        } else {
            const float mean = wsum(snv) * (1.0f / 64.0f);
            const float d = snv - mean;
            const float var = wsum(d * d) * (1.0f / 64.0f);
            const float rs = rsqrtf(var + 1e-5f);
            const float sn = d * rs * lsg[lane] + lsb[lane];
            sw[384 + lane] = sn;
            __builtin_amdgcn_wave_barrier();
            float q = 0.f;
            #pragma unroll 8
            for (int i = 0; i < 64; ++i) q = fmaf(sw[384 + i], Wq[i * 64 + lane], q);
            sw[448 + lane] = q * 0.125f;
            __builtin_amdgcn_wave_barrier();
            float kq = 0.f;
            #pragma unroll 8
            for (int p = 0; p < 64; ++p) kq = fmaf(WkT[p * 64 + lane], sw[448 + p], kq);
            const float bk = wsum(lib[lane] * kq);
            const float gk = lig[lane] * kq;
            const float g1 = wsum(gk);
            gkq[r * 64 + lane] = gk;
            if (lane == 0) { aux[r * 2] = g1; aux[r * 2 + 1] = bk; }
            __builtin_amdgcn_wave_barrier();   // sw reads done before next si
        }
    }
}

// ---------------------------------------------------------------------------
extern "C" void kernel_launch(void* const* d_in, const int* in_sizes, int n_in,
                              void* d_out, int out_size, void* d_ws, size_t ws_size,
                              hipStream_t stream)
{
    const float* x   = (const float*)d_in[0];
    const float* lig = (const float*)d_in[1];
    const float* lib = (const float*)d_in[2];
    const float* lsg = (const float*)d_in[3];
    const float* lsb = (const float*)d_in[4];
    const float* s0  = (const float*)d_in[5];
    const float* Wk  = (const float*)d_in[6];
    const float* Wv  = (const float*)d_in[7];
    const float* Wq  = (const float*)d_in[8];
    const float* wih = (const float*)d_in[9];
    const float* whh = (const float*)d_in[10];
    const float* bih = (const float*)d_in[11];
    const float* bhh = (const float*)d_in[12];
    const float* w1  = (const float*)d_in[13];
    const float* b1  = (const float*)d_in[14];
    const float* w2  = (const float*)d_in[15];
    const float* b2  = (const float*)d_in[16];

    float* f = (float*)d_ws;
    float* gkq   = f; f += 448 * 64;
    float* aux   = f; f += 448 * 2;
    float* slots = f; f += 448 * 64;
    float* Ypart = f; f += (long)64 * 16 * 456;
    float* wihT  = f; f += 64 * 192;
    float* whhT  = f; f += 64 * 192;
    float* WkT   = f; f += 64 * 64;
    int*   cnt   = (int*)f; f += 64;

    init_kernel<<<112, 256, 0, stream>>>(s0, lsg, lsb, Wq, Wk, lig, lib,
                                         wih, whh, slots, gkq, aux,
                                         wihT, whhT, WkT, cnt);
    for (int it = 0; it < 3; ++it) {
        attn_kernel<<<1024, 256, 0, stream>>>(
            x, gkq, aux, Ypart, cnt, slots, Wv, wihT, whhT, bih, bhh,
            w1, b1, w2, b2, lsg, lsb, Wq, WkT, lig, lib,
            (float*)d_out, it == 2);
    }
}

// Round 6
// 424.056 us; speedup vs baseline: 1.2342x; 1.2342x over previous
//
#include <hip/hip_runtime.h>
#include <stdint.h>

#define L2E 1.44269504088896f

static __device__ __forceinline__ float wsum(float v) {
    #pragma unroll
    for (int m = 1; m < 64; m <<= 1) v += __shfl_xor(v, m, 64);
    return v;
}
static __device__ __forceinline__ float sigm(float x) {
    return 1.0f / (1.0f + __builtin_amdgcn_exp2f(-x * L2E));
}
static __device__ __forceinline__ float tanh_(float x) {
    const float ax = fabsf(x);
    const float t = __builtin_amdgcn_exp2f(-2.0f * ax * L2E);
    const float r = (1.0f - t) / (1.0f + t);
    return (x < 0.f) ? -r : r;
}

// ---------------------------------------------------------------------------
// init: weight transposes (wihT/whhT/WkT) + iter-0 gkq/aux.
// grid 112 x 256 (28672 thr = exact transpose element count).
// ---------------------------------------------------------------------------
__global__ __launch_bounds__(256) void init_kernel(
    const float* __restrict__ s0,
    const float* __restrict__ lsg, const float* __restrict__ lsb,
    const float* __restrict__ Wq,  const float* __restrict__ Wk,
    const float* __restrict__ lig, const float* __restrict__ lib,
    const float* __restrict__ wih, const float* __restrict__ whh,
    float* __restrict__ gkq, float* __restrict__ aux,
    float* __restrict__ wihT, float* __restrict__ whhT, float* __restrict__ WkT)
{
    __shared__ float wkT[4096];
    __shared__ float scr[4][64];
    const int tid = threadIdx.x, lane = tid & 63, wv = tid >> 6;
    const int idx = blockIdx.x * 256 + tid;

    if (idx < 12288) {
        const int i = idx / 192, j = idx - i * 192;
        wihT[idx] = wih[j * 64 + i];
    } else if (idx < 24576) {
        const int o = idx - 12288;
        const int i = o / 192, j = o - i * 192;
        whhT[o] = whh[j * 64 + i];
    } else {
        const int o = idx - 24576;
        const int p = o >> 6, d = o & 63;
        WkT[o] = Wk[d * 64 + p];
    }

    const int r = blockIdx.x * 4 + wv;          // 0..447
    const int s = r % 7;
    #pragma unroll
    for (int i = tid; i < 4096; i += 256) {
        const int d = i >> 6, p = i & 63;
        wkT[p * 64 + d] = Wk[i];
    }
    const float h = s0[s * 64 + lane];
    __syncthreads();

    const float mean = wsum(h) * (1.0f / 64.0f);
    const float d = h - mean;
    const float var = wsum(d * d) * (1.0f / 64.0f);
    const float rs = rsqrtf(var + 1e-5f);
    const float sn = d * rs * lsg[lane] + lsb[lane];
    scr[wv][lane] = sn;
    __syncthreads();
    float q = 0.f;
    #pragma unroll 8
    for (int i = 0; i < 64; ++i) q = fmaf(scr[wv][i], Wq[i * 64 + lane], q);
    q *= 0.125f;
    __syncthreads();
    scr[wv][lane] = q;
    __syncthreads();
    float kq = 0.f;
    #pragma unroll 8
    for (int p = 0; p < 64; ++p) kq = fmaf(wkT[p * 64 + lane], scr[wv][p], kq);
    const float bk = wsum(lib[lane] * kq);
    const float gk = lig[lane] * kq;
    const float g1 = wsum(gk);
    gkq[r * 64 + lane] = gk;
    if (lane == 0) { aux[r * 2] = g1; aux[r * 2 + 1] = bk; }
}

// ---------------------------------------------------------------------------
// attn helpers
// ---------------------------------------------------------------------------
static __device__ __forceinline__ void stage_store(float* xw, const float4* R, int lane)
{
    #pragma unroll
    for (int st = 0; st < 8; ++st) {
        const int row = st * 4 + (lane >> 4);
        const int dim = (lane & 15) * 4;
        float* d = xw + row * 65 + dim;
        d[0] = R[st].x; d[1] = R[st].y; d[2] = R[st].z; d[3] = R[st].w;
    }
}

static __device__ __forceinline__ void do_pass(
    float* __restrict__ xw, float* __restrict__ wshw,
    const float* __restrict__ gkql, const float* __restrict__ auxl,
    int q5, int h, float* Yr, float* cacc)
{
    float xf[32];
    float sum = 0.f, ss = 0.f;
    const float* xr = xw + q5 * 65 + h * 32;
    #pragma unroll
    for (int c = 0; c < 32; ++c) {
        xf[c] = xr[c];
        sum += xf[c];
        ss = fmaf(xf[c], xf[c], ss);
    }
    float acc[7];
    #pragma unroll
    for (int s = 0; s < 7; ++s) {
        float a = 0.f;
        const float* gk = &gkql[s * 64 + h * 32];
        #pragma unroll
        for (int c = 0; c < 32; ++c) a = fmaf(xf[c], gk[c], a);
        acc[s] = a;
    }
    sum += __shfl_xor(sum, 32, 64);
    ss  += __shfl_xor(ss, 32, 64);
    #pragma unroll
    for (int s = 0; s < 7; ++s) acc[s] += __shfl_xor(acc[s], 32, 64);

    const float m   = sum * (1.0f / 64.0f);
    const float var = ss * (1.0f / 64.0f) - m * m;
    const float rs  = rsqrtf(var + 1e-5f);
    const float rsm = rs * m;
    float t[7];
    #pragma unroll
    for (int s = 0; s < 7; ++s)
        t[s] = fmaf(rs, acc[s], fmaf(-rsm, auxl[2 * s], auxl[2 * s + 1]));
    float mx = t[0];
    #pragma unroll
    for (int s = 1; s < 7; ++s) mx = fmaxf(mx, t[s]);
    float e[7], se = 0.f;
    #pragma unroll
    for (int s = 0; s < 7; ++s) {
        e[s] = __builtin_amdgcn_exp2f((t[s] - mx) * L2E);
        se += e[s];
    }
    const float inv = 1.0f / se;
    #pragma unroll
    for (int s = 0; s < 7; ++s) {
        const float w = fmaf(e[s], inv, 1e-8f);
        cacc[s] += w;                           // counted by both halves: /2 later
        if (h == 0) wshw[q5 * 8 + s] = w * rs;
    }
    if (h == 0) wshw[q5 * 8 + 7] = 0.f;
    __builtin_amdgcn_wave_barrier();

    #pragma unroll 4
    for (int r2 = 0; r2 < 16; ++r2) {
        const int rr = r2 * 2 + h;
        const float4 p0 = *(const float4*)&wshw[rr * 8];
        const float4 p1 = *(const float4*)&wshw[rr * 8 + 4];
        const float v0 = xw[rr * 65 + q5 * 2];
        const float v1 = xw[rr * 65 + q5 * 2 + 1];
        const float ps[7] = {p0.x, p0.y, p0.z, p0.w, p1.x, p1.y, p1.z};
        #pragma unroll
        for (int s = 0; s < 7; ++s) {
            Yr[2 * s]     = fmaf(ps[s], v0, Yr[2 * s]);
            Yr[2 * s + 1] = fmaf(ps[s], v1, Yr[2 * s + 1]);
        }
    }
}

// ---------------------------------------------------------------------------
// attn (iter = 0,1,2). For iter>0 each block FIRST redundantly recomputes the
// previous iteration's slot update for its own batch (reads Ypart_prev written
// last dispatch -- cross-dispatch visibility, no fences/atomics) producing
// gkql/auxl directly in LDS; chunk-0 blocks also publish slots for the next
// dispatch. Then the attention pass writes Ypart_cur. grid B*16=1024 x 256.
// ---------------------------------------------------------------------------
__global__ __launch_bounds__(256) void attn_kernel(
    const float* __restrict__ x,
    const float* __restrict__ gkq, const float* __restrict__ aux,
    const float* __restrict__ Yprev, float* __restrict__ Ycur,
    const float* __restrict__ s0, const float* __restrict__ slots_in,
    float* __restrict__ slots_out,
    const float* __restrict__ Wv,
    const float* __restrict__ wihT, const float* __restrict__ whhT,
    const float* __restrict__ bih,  const float* __restrict__ bhh,
    const float* __restrict__ w1,   const float* __restrict__ b1,
    const float* __restrict__ w2,   const float* __restrict__ b2,
    const float* __restrict__ lsg,  const float* __restrict__ lsb,
    const float* __restrict__ Wq,   const float* __restrict__ WkT,
    const float* __restrict__ lig,  const float* __restrict__ lib,
    int iter)
{
    __shared__ float xsh[4][2080];              // 32 rows x 65 per wave
    __shared__ float wsh[4][256];
    __shared__ float gkql[448];
    __shared__ float auxl[14];
    const int tid = threadIdx.x, lane = tid & 63, wv = tid >> 6;
    const int b = blockIdx.x >> 4, chunk = blockIdx.x & 15;
    const int q5 = lane & 31, h = lane >> 5;

    // issue pass-0 x loads immediately (fly during prefix / gkql setup)
    const float* tbase = x + (((long)b * 4096) + chunk * 256 + wv * 64) * 64;
    float4 Ra[8];
    {
        const float4* srcA = (const float4*)tbase;
        #pragma unroll
        for (int st = 0; st < 8; ++st) Ra[st] = srcA[st * 64 + lane];
    }

    if (iter == 0) {
        gkql[tid] = gkq[b * 448 + tid];
        if (tid < 192) gkql[tid + 256] = gkq[b * 448 + tid + 256];
        if (tid < 14) auxl[tid] = aux[b * 14 + tid];
    } else {
        // ---- redundant slot-update prefix (wave-local; no block barriers) ----
        float* sw = &xsh[wv][0];
        const float* Yb = Yprev + (long)b * 16 * 456;
        #pragma unroll 1
        for (int si = 0; si < 2; ++si) {
            const int s = wv + si * 4;
            if (s >= 7) break;
            const int r = b * 7 + s;

            float Yd = 0.f, C = 0.f;
            #pragma unroll
            for (int c = 0; c < 16; ++c) {
                Yd += Yb[c * 456 + s * 64 + lane];
                C  += Yb[c * 456 + 448 + s];
            }
            const float Z = wsum(Yd) * (1.0f / 64.0f);
            const float aoc = (lig[lane] * (Yd - Z) + lib[lane] * C) / C;
            sw[lane] = aoc;
            __builtin_amdgcn_wave_barrier();
            float u = 0.f;
            #pragma unroll 8
            for (int i = 0; i < 64; ++i) u = fmaf(sw[i], Wv[i * 64 + lane], u);
            const float hv = (iter == 1) ? s0[s * 64 + lane]
                                         : slots_in[r * 64 + lane];
            __builtin_amdgcn_wave_barrier();
            sw[64 + lane] = u; sw[128 + lane] = hv;
            __builtin_amdgcn_wave_barrier();

            float gi[3], gh[3];
            #pragma unroll
            for (int g = 0; g < 3; ++g) {
                const int j = g * 64 + lane;
                float a1 = bih[j], a2 = bhh[j];
                #pragma unroll 8
                for (int i = 0; i < 64; ++i) {
                    a1 = fmaf(sw[64 + i],  wihT[i * 192 + j], a1);
                    a2 = fmaf(sw[128 + i], whhT[i * 192 + j], a2);
                }
                gi[g] = a1; gh[g] = a2;
            }
            const float rr = sigm(gi[0] + gh[0]);
            const float zz = sigm(gi[1] + gh[1]);
            const float nn = tanh_(gi[2] + rr * gh[2]);
            const float hn = (1.f - zz) * nn + zz * hv;
            sw[192 + lane] = hn;
            __builtin_amdgcn_wave_barrier();

            float m0 = b1[lane], m1 = b1[64 + lane];
            #pragma unroll 8
            for (int i = 0; i < 64; ++i) {
                const float hni = sw[192 + i];
                m0 = fmaf(hni, w1[i * 128 + lane], m0);
                m1 = fmaf(hni, w1[i * 128 + 64 + lane], m1);
            }
            m0 = fmaxf(m0, 0.f); m1 = fmaxf(m1, 0.f);
            sw[256 + lane] = m0; sw[320 + lane] = m1;
            __builtin_amdgcn_wave_barrier();
            float o = b2[lane];
            #pragma unroll 8
            for (int t = 0; t < 128; ++t)
                o = fmaf(sw[256 + t], w2[t * 64 + lane], o);
            const float snv = hn + o;
            if (chunk == 0) slots_out[r * 64 + lane] = snv;

            const float mean = wsum(snv) * (1.0f / 64.0f);
            const float d = snv - mean;
            const float var = wsum(d * d) * (1.0f / 64.0f);
            const float rs = rsqrtf(var + 1e-5f);
            const float sn = d * rs * lsg[lane] + lsb[lane];
            sw[384 + lane] = sn;
            __builtin_amdgcn_wave_barrier();
            float q = 0.f;
            #pragma unroll 8
            for (int i = 0; i < 64; ++i) q = fmaf(sw[384 + i], Wq[i * 64 + lane], q);
            sw[448 + lane] = q * 0.125f;
            __builtin_amdgcn_wave_barrier();
            float kq = 0.f;
            #pragma unroll 8
            for (int p = 0; p < 64; ++p) kq = fmaf(WkT[p * 64 + lane], sw[448 + p], kq);
            const float bk = wsum(lib[lane] * kq);
            const float gk = lig[lane] * kq;
            const float g1 = wsum(gk);
            gkql[s * 64 + lane] = gk;
            if (lane == 0) { auxl[2 * s] = g1; auxl[2 * s + 1] = bk; }
            __builtin_amdgcn_wave_barrier();
        }
    }
    __syncthreads();

    // ---- attention main ----
    float Yr[14];
    #pragma unroll
    for (int i = 0; i < 14; ++i) Yr[i] = 0.f;
    float cacc[7] = {0.f, 0.f, 0.f, 0.f, 0.f, 0.f, 0.f};
    float* xw = &xsh[wv][0];
    float* wshw = &wsh[wv][0];

    stage_store(xw, Ra, lane);
    float4 Rb[8];
    {
        const float4* srcB = (const float4*)(tbase + 2048);
        #pragma unroll
        for (int st = 0; st < 8; ++st) Rb[st] = srcB[st * 64 + lane];
    }
    do_pass(xw, wshw, gkql, auxl, q5, h, Yr, cacc);
    __builtin_amdgcn_wave_barrier();
    stage_store(xw, Rb, lane);
    do_pass(xw, wshw, gkql, auxl, q5, h, Yr, cacc);

    #pragma unroll
    for (int i = 0; i < 14; ++i) Yr[i] += __shfl_xor(Yr[i], 32, 64);
    __builtin_amdgcn_wave_barrier();
    if (h == 0) {
        #pragma unroll
        for (int s = 0; s < 7; ++s) {
            xw[s * 64 + q5 * 2]     = Yr[2 * s];
            xw[s * 64 + q5 * 2 + 1] = Yr[2 * s + 1];
        }
    }
    #pragma unroll
    for (int s = 0; s < 7; ++s) {
        const float Cs = wsum(cacc[s]) * 0.5f;
        if (lane == 0) xw[448 + s] = Cs;
    }
    __syncthreads();
    for (int i = tid; i < 455; i += 256)
        Ycur[((long)b * 16 + chunk) * 456 + i] =
            xsh[0][i] + xsh[1][i] + xsh[2][i] + xsh[3][i];
}

// ---------------------------------------------------------------------------
// final: update from Ypart(2) + slots(2) -> d_out. grid 448 x 256.
// ---------------------------------------------------------------------------
__global__ __launch_bounds__(256) void final_kernel(
    const float* __restrict__ Ypart, const float* __restrict__ slots_in,
    const float* __restrict__ Wv,
    const float* __restrict__ wihT, const float* __restrict__ whhT,
    const float* __restrict__ bih,  const float* __restrict__ bhh,
    const float* __restrict__ w1,   const float* __restrict__ b1,
    const float* __restrict__ w2,   const float* __restrict__ b2,
    const float* __restrict__ lig,  const float* __restrict__ lib,
    float* __restrict__ out)
{
    __shared__ float red[4][64];
    __shared__ float c16[16];
    __shared__ float ash[64];
    __shared__ float ush[64];
    __shared__ float hsh[64];
    __shared__ float gish[192], ghsh[192];
    __shared__ float hnsh[64];
    __shared__ float mbsh[128];
    const int tid = threadIdx.x, lane = tid & 63, wv = tid >> 6;
    const int r = blockIdx.x;
    const int b = r / 7, s = r - b * 7;
    const float* Yb = Ypart + (long)b * 16 * 456;

    float yp = 0.f;
    #pragma unroll
    for (int c = 0; c < 4; ++c)
        yp += Yb[(wv * 4 + c) * 456 + s * 64 + lane];
    red[wv][lane] = yp;
    if (tid < 16) c16[tid] = Yb[tid * 456 + 448 + s];
    if (tid >= 64 && tid < 128) hsh[tid - 64] = slots_in[r * 64 + (tid - 64)];
    __syncthreads();

    if (tid < 64) {
        const float Yd = red[0][lane] + red[1][lane] + red[2][lane] + red[3][lane];
        float C = 0.f;
        #pragma unroll
        for (int c = 0; c < 16; ++c) C += c16[c];
        const float Z = wsum(Yd) * (1.0f / 64.0f);
        ash[lane] = (lig[lane] * (Yd - Z) + lib[lane] * C) / C;
    }
    __syncthreads();

    float up = 0.f;
    #pragma unroll
    for (int i = 0; i < 16; ++i) {
        const int ii = wv * 16 + i;
        up = fmaf(ash[ii], Wv[ii * 64 + lane], up);
    }
    red[wv][lane] = up;
    __syncthreads();
    if (tid < 64) ush[lane] = red[0][lane] + red[1][lane] + red[2][lane] + red[3][lane];
    __syncthreads();

    if (tid < 192) {
        float a1 = bih[tid], a2 = bhh[tid];
        #pragma unroll 8
        for (int i = 0; i < 64; ++i) {
            a1 = fmaf(ush[i], wihT[i * 192 + tid], a1);
            a2 = fmaf(hsh[i], whhT[i * 192 + tid], a2);
        }
        gish[tid] = a1; ghsh[tid] = a2;
    }
    __syncthreads();
    if (tid < 64) {
        const float rr = sigm(gish[tid] + ghsh[tid]);
        const float zz = sigm(gish[64 + tid] + ghsh[64 + tid]);
        const float nn = tanh_(gish[128 + tid] + rr * ghsh[128 + tid]);
        hnsh[tid] = (1.f - zz) * nn + zz * hsh[tid];
    }
    __syncthreads();
    if (tid < 128) {
        float m = b1[tid];
        #pragma unroll 8
        for (int i = 0; i < 64; ++i) m = fmaf(hnsh[i], w1[i * 128 + tid], m);
        mbsh[tid] = fmaxf(m, 0.f);
    }
    __syncthreads();
    if (tid < 64) {
        float o = b2[tid];
        #pragma unroll 8
        for (int t = 0; t < 128; ++t) o = fmaf(mbsh[t], w2[t * 64 + tid], o);
        out[r * 64 + tid] = hnsh[tid] + o;
    }
}

// ---------------------------------------------------------------------------
extern "C" void kernel_launch(void* const* d_in, const int* in_sizes, int n_in,
                              void* d_out, int out_size, void* d_ws, size_t ws_size,
                              hipStream_t stream)
{
    const float* x   = (const float*)d_in[0];
    const float* lig = (const float*)d_in[1];
    const float* lib = (const float*)d_in[2];
    const float* lsg = (const float*)d_in[3];
    const float* lsb = (const float*)d_in[4];
    const float* s0  = (const float*)d_in[5];
    const float* Wk  = (const float*)d_in[6];
    const float* Wv  = (const float*)d_in[7];
    const float* Wq  = (const float*)d_in[8];
    const float* wih = (const float*)d_in[9];
    const float* whh = (const float*)d_in[10];
    const float* bih = (const float*)d_in[11];
    const float* bhh = (const float*)d_in[12];
    const float* w1  = (const float*)d_in[13];
    const float* b1  = (const float*)d_in[14];
    const float* w2  = (const float*)d_in[15];
    const float* b2  = (const float*)d_in[16];

    float* f = (float*)d_ws;
    float* gkq    = f; f += 448 * 64;
    float* aux    = f; f += 448 * 2;
    float* slotsA = f; f += 448 * 64;       // written by A1, read by A2
    float* slotsB = f; f += 448 * 64;       // written by A2, read by final
    float* YA     = f; f += (long)64 * 16 * 456;
    float* YB     = f; f += (long)64 * 16 * 456;
    float* wihT   = f; f += 64 * 192;
    float* whhT   = f; f += 64 * 192;
    float* WkT    = f; f += 64 * 64;

    init_kernel<<<112, 256, 0, stream>>>(s0, lsg, lsb, Wq, Wk, lig, lib,
                                         wih, whh, gkq, aux, wihT, whhT, WkT);
    // iter 0: no prefix, writes YA
    attn_kernel<<<1024, 256, 0, stream>>>(
        x, gkq, aux, YB, YA, s0, (const float*)nullptr, slotsA,
        Wv, wihT, whhT, bih, bhh, w1, b1, w2, b2, lsg, lsb, Wq, WkT, lig, lib, 0);
    // iter 1: prefix(update0 from YA, h=s0) -> writes slotsA, YB
    attn_kernel<<<1024, 256, 0, stream>>>(
        x, gkq, aux, YA, YB, s0, (const float*)nullptr, slotsA,
        Wv, wihT, whhT, bih, bhh, w1, b1, w2, b2, lsg, lsb, Wq, WkT, lig, lib, 1);
    // iter 2: prefix(update1 from YB, h=slotsA) -> writes slotsB, YA
    attn_kernel<<<1024, 256, 0, stream>>>(
        x, gkq, aux, YB, YA, s0, slotsA, slotsB,
        Wv, wihT, whhT, bih, bhh, w1, b1, w2, b2, lsg, lsb, Wq, WkT, lig, lib, 2);
    // final: update2 from YA + slotsB -> d_out
    final_kernel<<<448, 256, 0, stream>>>(
        YA, slotsB, Wv, wihT, whhT, bih, bhh, w1, b1, w2, b2, lig, lib,
        (float*)d_out);
}

// Round 7
// 343.726 us; speedup vs baseline: 1.5227x; 1.2337x over previous
//
#include <hip/hip_runtime.h>
#include <stdint.h>

#define L2E 1.44269504088896f

static __device__ __forceinline__ float wsum(float v) {
    #pragma unroll
    for (int m = 1; m < 64; m <<= 1) v += __shfl_xor(v, m, 64);
    return v;
}
static __device__ __forceinline__ float sigm(float x) {
    return 1.0f / (1.0f + __builtin_amdgcn_exp2f(-x * L2E));
}
static __device__ __forceinline__ float tanh_(float x) {
    const float ax = fabsf(x);
    const float t = __builtin_amdgcn_exp2f(-2.0f * ax * L2E);
    const float r = (1.0f - t) / (1.0f + t);
    return (x < 0.f) ? -r : r;
}

// ---------------------------------------------------------------------------
// init: weight transposes (wihT/whhT/WkT) + iter-0 gkq/aux.
// grid 112 x 256 (28672 thr = exact transpose element count).
// ---------------------------------------------------------------------------
__global__ __launch_bounds__(256) void init_kernel(
    const float* __restrict__ s0,
    const float* __restrict__ lsg, const float* __restrict__ lsb,
    const float* __restrict__ Wq,  const float* __restrict__ Wk,
    const float* __restrict__ lig, const float* __restrict__ lib,
    const float* __restrict__ wih, const float* __restrict__ whh,
    float* __restrict__ gkq, float* __restrict__ aux,
    float* __restrict__ wihT, float* __restrict__ whhT, float* __restrict__ WkT)
{
    __shared__ float wkT[4096];
    __shared__ float scr[4][64];
    const int tid = threadIdx.x, lane = tid & 63, wv = tid >> 6;
    const int idx = blockIdx.x * 256 + tid;

    if (idx < 12288) {
        const int i = idx / 192, j = idx - i * 192;
        wihT[idx] = wih[j * 64 + i];
    } else if (idx < 24576) {
        const int o = idx - 12288;
        const int i = o / 192, j = o - i * 192;
        whhT[o] = whh[j * 64 + i];
    } else {
        const int o = idx - 24576;
        const int p = o >> 6, d = o & 63;
        WkT[o] = Wk[d * 64 + p];
    }

    const int r = blockIdx.x * 4 + wv;          // 0..447
    const int s = r % 7;
    #pragma unroll
    for (int i = tid; i < 4096; i += 256) {
        const int d = i >> 6, p = i & 63;
        wkT[p * 64 + d] = Wk[i];
    }
    const float h = s0[s * 64 + lane];
    __syncthreads();

    const float mean = wsum(h) * (1.0f / 64.0f);
    const float d = h - mean;
    const float var = wsum(d * d) * (1.0f / 64.0f);
    const float rs = rsqrtf(var + 1e-5f);
    const float sn = d * rs * lsg[lane] + lsb[lane];
    scr[wv][lane] = sn;
    __syncthreads();
    float q = 0.f;
    #pragma unroll 8
    for (int i = 0; i < 64; ++i) q = fmaf(scr[wv][i], Wq[i * 64 + lane], q);
    q *= 0.125f;
    __syncthreads();
    scr[wv][lane] = q;
    __syncthreads();
    float kq = 0.f;
    #pragma unroll 8
    for (int p = 0; p < 64; ++p) kq = fmaf(wkT[p * 64 + lane], scr[wv][p], kq);
    const float bk = wsum(lib[lane] * kq);
    const float gk = lig[lane] * kq;
    const float g1 = wsum(gk);
    gkq[r * 64 + lane] = gk;
    if (lane == 0) { aux[r * 2] = g1; aux[r * 2 + 1] = bk; }
}

// ---------------------------------------------------------------------------
// attn (iter = 0,1,2). iter>0: each block redundantly recomputes the previous
// slot update for its batch from Yprev (cross-dispatch data, no fences),
// producing gkql/auxl in LDS; chunk-0 blocks publish slots for the next
// dispatch. Attention main = R3-proposal structure (measured fast): in-loop
// LDS staging, no register prefetch, no scheduling fences in the main.
// grid B*16 = 1024 x 256.
// ---------------------------------------------------------------------------
__global__ __launch_bounds__(256) void attn_kernel(
    const float* __restrict__ x,
    const float* __restrict__ gkq, const float* __restrict__ aux,
    const float* __restrict__ Yprev, float* __restrict__ Ycur,
    const float* __restrict__ s0, const float* __restrict__ slots_in,
    float* __restrict__ slots_out,
    const float* __restrict__ Wv,
    const float* __restrict__ wihT, const float* __restrict__ whhT,
    const float* __restrict__ bih,  const float* __restrict__ bhh,
    const float* __restrict__ w1,   const float* __restrict__ b1,
    const float* __restrict__ w2,   const float* __restrict__ b2,
    const float* __restrict__ lsg,  const float* __restrict__ lsb,
    const float* __restrict__ Wq,   const float* __restrict__ WkT,
    const float* __restrict__ lig,  const float* __restrict__ lib,
    int iter)
{
    __shared__ float xsh[4][2080];              // 32 rows x 65 (pad) per wave
    __shared__ float wsh[4][32][8];
    __shared__ float gkql[448];
    __shared__ float auxl[14];
    __shared__ float ybuf[4][456];
    __shared__ float pscr[4][192];              // prefix scratch
    const int tid = threadIdx.x, lane = tid & 63, wv = tid >> 6;
    const int b = blockIdx.x >> 4, chunk = blockIdx.x & 15;

    if (iter == 0) {
        gkql[tid] = gkq[b * 448 + tid];
        if (tid < 192) gkql[tid + 256] = gkq[b * 448 + tid + 256];
        if (tid < 14) auxl[tid] = aux[b * 14 + tid];
    } else {
        // ---- redundant slot-update prefix (wave-local sync only) ----
        float* sw = &pscr[wv][0];
        const float* Yb = Yprev + (long)b * 16 * 456;
        #pragma unroll 1
        for (int si = 0; si < 2; ++si) {
            const int s = wv + si * 4;
            if (s >= 7) break;
            const int r = b * 7 + s;

            float Yd = 0.f, C = 0.f;
            #pragma unroll
            for (int c = 0; c < 16; ++c) {
                Yd += Yb[c * 456 + s * 64 + lane];
                C  += Yb[c * 456 + 448 + s];
            }
            const float Z = wsum(Yd) * (1.0f / 64.0f);
            const float aoc = (lig[lane] * (Yd - Z) + lib[lane] * C) / C;
            sw[lane] = aoc;
            __builtin_amdgcn_wave_barrier();
            float u = 0.f;
            #pragma unroll 8
            for (int i = 0; i < 64; ++i) u = fmaf(sw[i], Wv[i * 64 + lane], u);
            const float hv = (iter == 1) ? s0[s * 64 + lane]
                                         : slots_in[r * 64 + lane];
            __builtin_amdgcn_wave_barrier();
            sw[64 + lane] = u; sw[128 + lane] = hv;
            __builtin_amdgcn_wave_barrier();

            float gi[3], gh[3];
            #pragma unroll
            for (int g = 0; g < 3; ++g) {
                const int j = g * 64 + lane;
                float a1 = bih[j], a2 = bhh[j];
                #pragma unroll 8
                for (int i = 0; i < 64; ++i) {
                    a1 = fmaf(sw[64 + i],  wihT[i * 192 + j], a1);
                    a2 = fmaf(sw[128 + i], whhT[i * 192 + j], a2);
                }
                gi[g] = a1; gh[g] = a2;
            }
            const float rr = sigm(gi[0] + gh[0]);
            const float zz = sigm(gi[1] + gh[1]);
            const float nn = tanh_(gi[2] + rr * gh[2]);
            const float hn = (1.f - zz) * nn + zz * hv;
            __builtin_amdgcn_wave_barrier();
            sw[lane] = hn;                      // aoc region dead
            __builtin_amdgcn_wave_barrier();

            float m0 = b1[lane], m1 = b1[64 + lane];
            #pragma unroll 8
            for (int i = 0; i < 64; ++i) {
                const float hni = sw[i];
                m0 = fmaf(hni, w1[i * 128 + lane], m0);
                m1 = fmaf(hni, w1[i * 128 + 64 + lane], m1);
            }
            m0 = fmaxf(m0, 0.f); m1 = fmaxf(m1, 0.f);
            __builtin_amdgcn_wave_barrier();
            sw[64 + lane] = m0; sw[128 + lane] = m1;   // u,hv regions dead
            __builtin_amdgcn_wave_barrier();
            float o = b2[lane];
            #pragma unroll 8
            for (int t = 0; t < 128; ++t)
                o = fmaf(sw[64 + t], w2[t * 64 + lane], o);
            const float snv = hn + o;
            if (chunk == 0) slots_out[r * 64 + lane] = snv;

            const float mean = wsum(snv) * (1.0f / 64.0f);
            const float d = snv - mean;
            const float var = wsum(d * d) * (1.0f / 64.0f);
            const float rs = rsqrtf(var + 1e-5f);
            const float sn = d * rs * lsg[lane] + lsb[lane];
            __builtin_amdgcn_wave_barrier();
            sw[lane] = sn;                      // hn region dead
            __builtin_amdgcn_wave_barrier();
            float q = 0.f;
            #pragma unroll 8
            for (int i = 0; i < 64; ++i) q = fmaf(sw[i], Wq[i * 64 + lane], q);
            __builtin_amdgcn_wave_barrier();
            sw[64 + lane] = q * 0.125f;         // m0 region dead
            __builtin_amdgcn_wave_barrier();
            float kq = 0.f;
            #pragma unroll 8
            for (int p = 0; p < 64; ++p) kq = fmaf(WkT[p * 64 + lane], sw[64 + p], kq);
            const float bk = wsum(lib[lane] * kq);
            const float gk = lig[lane] * kq;
            const float g1 = wsum(gk);
            gkql[s * 64 + lane] = gk;
            if (lane == 0) { auxl[2 * s] = g1; auxl[2 * s + 1] = bk; }
            __builtin_amdgcn_wave_barrier();
        }
    }
    __syncthreads();

    // ---- attention main (R3 structure) ----
    const int q5 = lane & 31, h = lane >> 5;
    float Yr[14];
    #pragma unroll
    for (int i = 0; i < 14; ++i) Yr[i] = 0.f;
    float cacc[7] = {0.f, 0.f, 0.f, 0.f, 0.f, 0.f, 0.f};

    const float* tbase = x + (((long)b * 4096) + chunk * 256 + wv * 64) * 64;
    #pragma unroll 1
    for (int pass = 0; pass < 2; ++pass) {
        // coalesced stage: 32 rows x 64 dims -> LDS (pad 65)
        const float4* src = (const float4*)(tbase + pass * 2048);
        #pragma unroll
        for (int st = 0; st < 8; ++st) {
            const float4 d4 = src[st * 64 + lane];
            const int f = (st * 64 + lane) * 4;
            const int row = (f >> 6) & 31, dim = f & 63;
            float* dst = &xsh[wv][row * 65 + dim];
            dst[0] = d4.x; dst[1] = d4.y; dst[2] = d4.z; dst[3] = d4.w;
        }
        // same-wave producer/consumer: LDS ops in order, no barrier.

        // Phase A: row = q5, dims h*32..h*32+31
        float xf[32];
        float sum = 0.f, ss = 0.f;
        const float* xr = &xsh[wv][q5 * 65 + h * 32];
        #pragma unroll
        for (int c = 0; c < 32; ++c) {
            xf[c] = xr[c];
            sum += xf[c];
            ss = fmaf(xf[c], xf[c], ss);
        }
        float acc[7];
        #pragma unroll
        for (int s = 0; s < 7; ++s) {
            float a = 0.f;
            const float* gk = &gkql[s * 64 + h * 32];
            #pragma unroll
            for (int c = 0; c < 32; ++c) a = fmaf(xf[c], gk[c], a);
            acc[s] = a;
        }
        sum += __shfl_xor(sum, 32, 64);
        ss  += __shfl_xor(ss, 32, 64);
        #pragma unroll
        for (int s = 0; s < 7; ++s) acc[s] += __shfl_xor(acc[s], 32, 64);

        const float m   = sum * (1.0f / 64.0f);
        const float var = ss * (1.0f / 64.0f) - m * m;
        const float rs  = rsqrtf(var + 1e-5f);
        const float rsm = rs * m;
        float t[7];
        #pragma unroll
        for (int s = 0; s < 7; ++s)
            t[s] = fmaf(rs, acc[s], fmaf(-rsm, auxl[2 * s], auxl[2 * s + 1]));
        float mx = t[0];
        #pragma unroll
        for (int s = 1; s < 7; ++s) mx = fmaxf(mx, t[s]);
        float e[7], se = 0.f;
        #pragma unroll
        for (int s = 0; s < 7; ++s) {
            e[s] = __builtin_amdgcn_exp2f((t[s] - mx) * L2E);
            se += e[s];
        }
        const float inv = 1.0f / se;
        #pragma unroll
        for (int s = 0; s < 7; ++s) {
            const float w = fmaf(e[s], inv, 1e-8f);
            cacc[s] += w;                       // both halves count: /2 later
            if (h == 0) wsh[wv][q5][s] = w * rs;
        }
        if (h == 0) wsh[wv][q5][7] = 0.f;

        // Phase B: rows 2*r2+h, dims q5*2, q5*2+1
        #pragma unroll 4
        for (int r2 = 0; r2 < 16; ++r2) {
            const int rr = r2 * 2 + h;
            const float4 p0 = *(const float4*)&wsh[wv][rr][0];
            const float4 p1 = *(const float4*)&wsh[wv][rr][4];
            const float v0 = xsh[wv][rr * 65 + q5 * 2];
            const float v1 = xsh[wv][rr * 65 + q5 * 2 + 1];
            const float ps[7] = {p0.x, p0.y, p0.z, p0.w, p1.x, p1.y, p1.z};
            #pragma unroll
            for (int s = 0; s < 7; ++s) {
                Yr[2 * s]     = fmaf(ps[s], v0, Yr[2 * s]);
                Yr[2 * s + 1] = fmaf(ps[s], v1, Yr[2 * s + 1]);
            }
        }
    }

    // wave reduce + block reduce -> Ycur
    #pragma unroll
    for (int i = 0; i < 14; ++i) Yr[i] += __shfl_xor(Yr[i], 32, 64);
    if (h == 0) {
        #pragma unroll
        for (int s = 0; s < 7; ++s) {
            ybuf[wv][s * 64 + q5 * 2]     = Yr[2 * s];
            ybuf[wv][s * 64 + q5 * 2 + 1] = Yr[2 * s + 1];
        }
    }
    #pragma unroll
    for (int s = 0; s < 7; ++s) {
        const float Cs = wsum(cacc[s]) * 0.5f;
        if (lane == 0) ybuf[wv][448 + s] = Cs;
    }
    __syncthreads();
    for (int i = tid; i < 455; i += 256)
        Ycur[((long)b * 16 + chunk) * 456 + i] =
            ybuf[0][i] + ybuf[1][i] + ybuf[2][i] + ybuf[3][i];
}

// ---------------------------------------------------------------------------
// final: update from Ypart(2) + slots(2) -> d_out. grid 448 x 256.
// ---------------------------------------------------------------------------
__global__ __launch_bounds__(256) void final_kernel(
    const float* __restrict__ Ypart, const float* __restrict__ slots_in,
    const float* __restrict__ Wv,
    const float* __restrict__ wihT, const float* __restrict__ whhT,
    const float* __restrict__ bih,  const float* __restrict__ bhh,
    const float* __restrict__ w1,   const float* __restrict__ b1,
    const float* __restrict__ w2,   const float* __restrict__ b2,
    const float* __restrict__ lig,  const float* __restrict__ lib,
    float* __restrict__ out)
{
    __shared__ float red[4][64];
    __shared__ float c16[16];
    __shared__ float ash[64];
    __shared__ float ush[64];
    __shared__ float hsh[64];
    __shared__ float gish[192], ghsh[192];
    __shared__ float hnsh[64];
    __shared__ float mbsh[128];
    const int tid = threadIdx.x, lane = tid & 63, wv = tid >> 6;
    const int r = blockIdx.x;
    const int b = r / 7, s = r - b * 7;
    const float* Yb = Ypart + (long)b * 16 * 456;

    float yp = 0.f;
    #pragma unroll
    for (int c = 0; c < 4; ++c)
        yp += Yb[(wv * 4 + c) * 456 + s * 64 + lane];
    red[wv][lane] = yp;
    if (tid < 16) c16[tid] = Yb[tid * 456 + 448 + s];
    if (tid >= 64 && tid < 128) hsh[tid - 64] = slots_in[r * 64 + (tid - 64)];
    __syncthreads();

    if (tid < 64) {
        const float Yd = red[0][lane] + red[1][lane] + red[2][lane] + red[3][lane];
        float C = 0.f;
        #pragma unroll
        for (int c = 0; c < 16; ++c) C += c16[c];
        const float Z = wsum(Yd) * (1.0f / 64.0f);
        ash[lane] = (lig[lane] * (Yd - Z) + lib[lane] * C) / C;
    }
    __syncthreads();

    float up = 0.f;
    #pragma unroll
    for (int i = 0; i < 16; ++i) {
        const int ii = wv * 16 + i;
        up = fmaf(ash[ii], Wv[ii * 64 + lane], up);
    }
    red[wv][lane] = up;
    __syncthreads();
    if (tid < 64) ush[lane] = red[0][lane] + red[1][lane] + red[2][lane] + red[3][lane];
    __syncthreads();

    if (tid < 192) {
        float a1 = bih[tid], a2 = bhh[tid];
        #pragma unroll 8
        for (int i = 0; i < 64; ++i) {
            a1 = fmaf(ush[i], wihT[i * 192 + tid], a1);
            a2 = fmaf(hsh[i], whhT[i * 192 + tid], a2);
        }
        gish[tid] = a1; ghsh[tid] = a2;
    }
    __syncthreads();
    if (tid < 64) {
        const float rr = sigm(gish[tid] + ghsh[tid]);
        const float zz = sigm(gish[64 + tid] + ghsh[64 + tid]);
        const float nn = tanh_(gish[128 + tid] + rr * ghsh[128 + tid]);
        hnsh[tid] = (1.f - zz) * nn + zz * hsh[tid];
    }
    __syncthreads();
    if (tid < 128) {
        float m = b1[tid];
        #pragma unroll 8
        for (int i = 0; i < 64; ++i) m = fmaf(hnsh[i], w1[i * 128 + tid], m);
        mbsh[tid] = fmaxf(m, 0.f);
    }
    __syncthreads();
    if (tid < 64) {
        float o = b2[tid];
        #pragma unroll 8
        for (int t = 0; t < 128; ++t) o = fmaf(mbsh[t], w2[t * 64 + tid], o);
        out[r * 64 + tid] = hnsh[tid] + o;
    }
}

// ---------------------------------------------------------------------------
extern "C" void kernel_launch(void* const* d_in, const int* in_sizes, int n_in,
                              void* d_out, int out_size, void* d_ws, size_t ws_size,
                              hipStream_t stream)
{
    const float* x   = (const float*)d_in[0];
    const float* lig = (const float*)d_in[1];
    const float* lib = (const float*)d_in[2];
    const float* lsg = (const float*)d_in[3];
    const float* lsb = (const float*)d_in[4];
    const float* s0  = (const float*)d_in[5];
    const float* Wk  = (const float*)d_in[6];
    const float* Wv  = (const float*)d_in[7];
    const float* Wq  = (const float*)d_in[8];
    const float* wih = (const float*)d_in[9];
    const float* whh = (const float*)d_in[10];
    const float* bih = (const float*)d_in[11];
    const float* bhh = (const float*)d_in[12];
    const float* w1  = (const float*)d_in[13];
    const float* b1  = (const float*)d_in[14];
    const float* w2  = (const float*)d_in[15];
    const float* b2  = (const float*)d_in[16];

    float* f = (float*)d_ws;
    float* gkq    = f; f += 448 * 64;
    float* aux    = f; f += 448 * 2;
    float* slotsA = f; f += 448 * 64;       // written by A1, read by A2
    float* slotsB = f; f += 448 * 64;       // written by A2, read by final
    float* YA     = f; f += (long)64 * 16 * 456;
    float* YB     = f; f += (long)64 * 16 * 456;
    float* wihT   = f; f += 64 * 192;
    float* whhT   = f; f += 64 * 192;
    float* WkT    = f; f += 64 * 64;

    init_kernel<<<112, 256, 0, stream>>>(s0, lsg, lsb, Wq, Wk, lig, lib,
                                         wih, whh, gkq, aux, wihT, whhT, WkT);
    // iter 0: no prefix, writes YA
    attn_kernel<<<1024, 256, 0, stream>>>(
        x, gkq, aux, YB, YA, s0, (const float*)nullptr, slotsA,
        Wv, wihT, whhT, bih, bhh, w1, b1, w2, b2, lsg, lsb, Wq, WkT, lig, lib, 0);
    // iter 1: prefix(update0 from YA, h=s0) -> writes slotsA, YB
    attn_kernel<<<1024, 256, 0, stream>>>(
        x, gkq, aux, YA, YB, s0, (const float*)nullptr, slotsA,
        Wv, wihT, whhT, bih, bhh, w1, b1, w2, b2, lsg, lsb, Wq, WkT, lig, lib, 1);
    // iter 2: prefix(update1 from YB, h=slotsA) -> writes slotsB, YA
    attn_kernel<<<1024, 256, 0, stream>>>(
        x, gkq, aux, YB, YA, s0, slotsA, slotsB,
        Wv, wihT, whhT, bih, bhh, w1, b1, w2, b2, lsg, lsb, Wq, WkT, lig, lib, 2);
    // final: update2 from YA + slotsB -> d_out
    final_kernel<<<448, 256, 0, stream>>>(
        YA, slotsB, Wv, wihT, whhT, bih, bhh, w1, b1, w2, b2, lig, lib,
        (float*)d_out);
}

// Round 8
// 235.291 us; speedup vs baseline: 2.2244x; 1.4609x over previous
//
#include <hip/hip_runtime.h>
#include <stdint.h>

#define L2E 1.44269504088896f

static __device__ __forceinline__ float wsum(float v) {
    #pragma unroll
    for (int m = 1; m < 64; m <<= 1) v += __shfl_xor(v, m, 64);
    return v;
}
static __device__ __forceinline__ float sigm(float x) {
    return 1.0f / (1.0f + __builtin_amdgcn_exp2f(-x * L2E));
}
static __device__ __forceinline__ float tanh_(float x) {
    const float ax = fabsf(x);
    const float t = __builtin_amdgcn_exp2f(-2.0f * ax * L2E);
    const float r = (1.0f - t) / (1.0f + t);
    return (x < 0.f) ? -r : r;
}

// ---------------------------------------------------------------------------
// init: fused weight transpose (wihT/whhT/WkT) + slot broadcast + iter-0
// gkq/aux. grid 112 x 256 (28672 thr = exact transpose element count).
// ---------------------------------------------------------------------------
__global__ __launch_bounds__(256) void init_kernel(
    const float* __restrict__ s0,
    const float* __restrict__ lsg, const float* __restrict__ lsb,
    const float* __restrict__ Wq,  const float* __restrict__ Wk,
    const float* __restrict__ lig, const float* __restrict__ lib,
    const float* __restrict__ wih, const float* __restrict__ whh,
    float* __restrict__ slots, float* __restrict__ gkq, float* __restrict__ aux,
    float* __restrict__ wihT, float* __restrict__ whhT, float* __restrict__ WkT)
{
    __shared__ float wkT[4096];
    __shared__ float scr[4][64];
    const int tid = threadIdx.x, lane = tid & 63, wv = tid >> 6;
    const int idx = blockIdx.x * 256 + tid;

    if (idx < 12288) {
        const int i = idx / 192, j = idx - i * 192;
        wihT[idx] = wih[j * 64 + i];
    } else if (idx < 24576) {
        const int o = idx - 12288;
        const int i = o / 192, j = o - i * 192;
        whhT[o] = whh[j * 64 + i];
    } else {
        const int o = idx - 24576;
        const int p = o >> 6, d = o & 63;
        WkT[o] = Wk[d * 64 + p];
    }

    const int r = blockIdx.x * 4 + wv;          // 0..447
    const int s = r % 7;
    #pragma unroll
    for (int i = tid; i < 4096; i += 256) {
        const int d = i >> 6, p = i & 63;
        wkT[p * 64 + d] = Wk[i];
    }
    const float h = s0[s * 64 + lane];
    slots[r * 64 + lane] = h;
    __syncthreads();

    const float mean = wsum(h) * (1.0f / 64.0f);
    const float d = h - mean;
    const float var = wsum(d * d) * (1.0f / 64.0f);
    const float rs = rsqrtf(var + 1e-5f);
    const float sn = d * rs * lsg[lane] + lsb[lane];
    scr[wv][lane] = sn;
    __syncthreads();
    float q = 0.f;
    #pragma unroll 8
    for (int i = 0; i < 64; ++i) q = fmaf(scr[wv][i], Wq[i * 64 + lane], q);
    q *= 0.125f;
    __syncthreads();
    scr[wv][lane] = q;
    __syncthreads();
    float kq = 0.f;
    #pragma unroll 8
    for (int p = 0; p < 64; ++p) kq = fmaf(wkT[p * 64 + lane], scr[wv][p], kq);
    const float bk = wsum(lib[lane] * kq);
    const float gk = lig[lane] * kq;
    const float g1 = wsum(gk);
    gkq[r * 64 + lane] = gk;
    if (lane == 0) { aux[r * 2] = g1; aux[r * 2 + 1] = bk; }
}

// ---------------------------------------------------------------------------
// attn v2 (R4-exact): per wave, two 32-row passes. Coalesced global->LDS x
// staging (pad 65). Phase A: 2 lanes/row, 32 dims each, one shfl_xor(32)
// combine; softmax; w*rs -> wsh. Phase B: reads x and wsh from LDS,
// accumulates Y[14]/lane. Block reduce -> Ypart[b][chunk][456]
// (448 Y + 7 colsums + pad). Z is NOT stored (Z = sum_d Y / 64 in update).
// grid B*16 = 1024 x 256.
// ---------------------------------------------------------------------------
__global__ __launch_bounds__(256) void attn_kernel(
    const float* __restrict__ x,
    const float* __restrict__ gkq, const float* __restrict__ aux,
    float* __restrict__ Ypart)
{
    __shared__ float xsh[4][32 * 65];
    __shared__ float wsh[4][32][8];
    __shared__ float gkql[448];
    __shared__ float auxl[14];
    __shared__ float ybuf[4][456];
    const int tid = threadIdx.x, lane = tid & 63, wv = tid >> 6;
    const int b = blockIdx.x >> 4, chunk = blockIdx.x & 15;

    gkql[tid] = gkq[b * 448 + tid];
    if (tid < 192) gkql[tid + 256] = gkq[b * 448 + tid + 256];
    if (tid < 14) auxl[tid] = aux[b * 14 + tid];
    __syncthreads();

    const int q5 = lane & 31, h = lane >> 5;   // (row-in-pass, dim half)
    float Yr[14];
    #pragma unroll
    for (int i = 0; i < 14; ++i) Yr[i] = 0.f;
    float cacc[7] = {0.f, 0.f, 0.f, 0.f, 0.f, 0.f, 0.f};

    const float* tbase = x + (((long)b * 4096) + chunk * 256 + wv * 64) * 64;
    #pragma unroll 1
    for (int pass = 0; pass < 2; ++pass) {
        // ---- coalesced stage: 32 rows x 64 dims -> LDS (pad 65) ----
        const float4* src = (const float4*)(tbase + pass * 2048);
        #pragma unroll
        for (int st = 0; st < 8; ++st) {
            const float4 d4 = src[st * 64 + lane];
            const int f = (st * 64 + lane) * 4;
            const int row = f >> 6, dim = f & 63;
            float* dst = &xsh[wv][row * 65 + dim];
            dst[0] = d4.x; dst[1] = d4.y; dst[2] = d4.z; dst[3] = d4.w;
        }
        // same-wave producer/consumer: compiler orders LDS ops, no barrier.

        // ---- Phase A: row = q5, dims h*32..h*32+31 ----
        float xf[32];
        float sum = 0.f, ss = 0.f;
        const float* xr = &xsh[wv][q5 * 65 + h * 32];
        #pragma unroll
        for (int c = 0; c < 32; ++c) {
            xf[c] = xr[c];
            sum += xf[c];
            ss = fmaf(xf[c], xf[c], ss);
        }
        float acc[7];
        #pragma unroll
        for (int s = 0; s < 7; ++s) {
            float a = 0.f;
            const float* gk = &gkql[s * 64 + h * 32];
            #pragma unroll
            for (int c = 0; c < 32; ++c) a = fmaf(xf[c], gk[c], a);
            acc[s] = a;
        }
        sum += __shfl_xor(sum, 32, 64);
        ss  += __shfl_xor(ss, 32, 64);
        #pragma unroll
        for (int s = 0; s < 7; ++s) acc[s] += __shfl_xor(acc[s], 32, 64);

        const float m   = sum * (1.0f / 64.0f);
        const float var = ss * (1.0f / 64.0f) - m * m;
        const float rs  = rsqrtf(var + 1e-5f);
        const float rsm = rs * m;
        float t[7];
        #pragma unroll
        for (int s = 0; s < 7; ++s)
            t[s] = fmaf(rs, acc[s], fmaf(-rsm, auxl[2 * s], auxl[2 * s + 1]));
        float mx = t[0];
        #pragma unroll
        for (int s = 1; s < 7; ++s) mx = fmaxf(mx, t[s]);
        float e[7], se = 0.f;
        #pragma unroll
        for (int s = 0; s < 7; ++s) {
            e[s] = __builtin_amdgcn_exp2f((t[s] - mx) * L2E);
            se += e[s];
        }
        const float inv = 1.0f / se;
        #pragma unroll
        for (int s = 0; s < 7; ++s) {
            const float w = fmaf(e[s], inv, 1e-8f);
            cacc[s] += w;                       // both halves: x2, fixed below
            if (h == 0) wsh[wv][q5][s] = w * rs;
        }
        if (h == 0) wsh[wv][q5][7] = 0.f;

        // ---- Phase B: rr = 2*step+h rows, dims q5*2, q5*2+1 ----
        #pragma unroll 4
        for (int r2 = 0; r2 < 16; ++r2) {
            const int rr = r2 * 2 + h;
            const float4 p0 = *(const float4*)&wsh[wv][rr][0];
            const float4 p1 = *(const float4*)&wsh[wv][rr][4];
            const float v0 = xsh[wv][rr * 65 + q5 * 2];
            const float v1 = xsh[wv][rr * 65 + q5 * 2 + 1];
            const float ps[7] = {p0.x, p0.y, p0.z, p0.w, p1.x, p1.y, p1.z};
            #pragma unroll
            for (int s = 0; s < 7; ++s) {
                Yr[2 * s]     = fmaf(ps[s], v0, Yr[2 * s]);
                Yr[2 * s + 1] = fmaf(ps[s], v1, Yr[2 * s + 1]);
            }
        }
    }

    // ---- wave reduce + block reduce -> Ypart ----
    #pragma unroll
    for (int i = 0; i < 14; ++i) Yr[i] += __shfl_xor(Yr[i], 32, 64);
    if (h == 0) {
        #pragma unroll
        for (int s = 0; s < 7; ++s) {
            ybuf[wv][s * 64 + q5 * 2]     = Yr[2 * s];
            ybuf[wv][s * 64 + q5 * 2 + 1] = Yr[2 * s + 1];
        }
    }
    #pragma unroll
    for (int s = 0; s < 7; ++s) {
        const float Cs = wsum(cacc[s]) * 0.5f;   // each row counted twice
        if (lane == 0) ybuf[wv][448 + s] = Cs;
    }
    if (lane == 1) ybuf[wv][455] = 0.f;
    __syncthreads();
    for (int i = tid; i < 455; i += 256)
        Ypart[((long)b * 16 + chunk) * 456 + i] =
            ybuf[0][i] + ybuf[1][i] + ybuf[2][i] + ybuf[3][i];
}

// ---------------------------------------------------------------------------
// update v2 (R4-exact): one block (256 thr) per (b,s) row. All weight reads
// coalesced (wihT/whhT/WkT pre-transposed). Chain: Y/C reduce -> aoc ->
// u=(aoc@Wv) -> GRU -> MLP -> slots (+ next-iter LN/q/kq or final store).
// grid 448.
// ---------------------------------------------------------------------------
__global__ __launch_bounds__(256) void update_kernel(
    const float* __restrict__ Ypart, float* __restrict__ slots,
    const float* __restrict__ Wv,
    const float* __restrict__ wihT, const float* __restrict__ whhT,
    const float* __restrict__ bih,  const float* __restrict__ bhh,
    const float* __restrict__ w1,   const float* __restrict__ b1,
    const float* __restrict__ w2,   const float* __restrict__ b2,
    const float* __restrict__ lsg,  const float* __restrict__ lsb,
    const float* __restrict__ Wq,   const float* __restrict__ WkT,
    const float* __restrict__ lig,  const float* __restrict__ lib,
    float* __restrict__ gkq, float* __restrict__ aux,
    float* __restrict__ out, int last)
{
    __shared__ float red[4][64];
    __shared__ float c16[16];
    __shared__ float ash[64];
    __shared__ float ush[64];
    __shared__ float hsh[64];
    __shared__ float gish[192], ghsh[192];
    __shared__ float hnsh[64];
    __shared__ float mbsh[128];
    __shared__ float qsh[64];
    const int tid = threadIdx.x, lane = tid & 63, wv = tid >> 6;
    const int r = blockIdx.x;                   // 0..447
    const int b = r / 7, s = r - b * 7;
    const float* Yb = Ypart + (long)b * 16 * 456;

    // stage 1: Y partial sums (4 chunks per wave), colsum parts, h load
    float yp = 0.f;
    #pragma unroll
    for (int c = 0; c < 4; ++c)
        yp += Yb[(wv * 4 + c) * 456 + s * 64 + lane];
    red[wv][lane] = yp;
    if (tid < 16) c16[tid] = Yb[tid * 456 + 448 + s];
    if (tid >= 64 && tid < 128) hsh[tid - 64] = slots[r * 64 + (tid - 64)];
    __syncthreads();

    if (tid < 64) {                             // wave 0
        const float Yd = red[0][lane] + red[1][lane] + red[2][lane] + red[3][lane];
        float C = 0.f;
        #pragma unroll
        for (int c = 0; c < 16; ++c) C += c16[c];
        const float Z = wsum(Yd) * (1.0f / 64.0f);   // Z = sum_d Y / 64
        ash[lane] = (lig[lane] * (Yd - Z) + lib[lane] * C) / C;
    }
    __syncthreads();

    // stage 2: u = aoc @ Wv, i-split over 4 waves
    float up = 0.f;
    #pragma unroll
    for (int i = 0; i < 16; ++i) {
        const int ii = wv * 16 + i;
        up = fmaf(ash[ii], Wv[ii * 64 + lane], up);
    }
    red[wv][lane] = up;
    __syncthreads();
    if (tid < 64) ush[lane] = red[0][lane] + red[1][lane] + red[2][lane] + red[3][lane];
    __syncthreads();

    // stage 3: GRU gates (192 outputs, coalesced transposed weights)
    if (tid < 192) {
        float a1 = bih[tid], a2 = bhh[tid];
        #pragma unroll 8
        for (int i = 0; i < 64; ++i) {
            a1 = fmaf(ush[i], wihT[i * 192 + tid], a1);
            a2 = fmaf(hsh[i], whhT[i * 192 + tid], a2);
        }
        gish[tid] = a1; ghsh[tid] = a2;
    }
    __syncthreads();
    if (tid < 64) {
        const float rr = sigm(gish[tid] + ghsh[tid]);
        const float zz = sigm(gish[64 + tid] + ghsh[64 + tid]);
        const float nn = tanh_(gish[128 + tid] + rr * ghsh[128 + tid]);
        hnsh[tid] = (1.f - zz) * nn + zz * hsh[tid];
    }
    __syncthreads();

    // stage 4: MLP hidden (128 outputs)
    if (tid < 128) {
        float m = b1[tid];
        #pragma unroll 8
        for (int i = 0; i < 64; ++i) m = fmaf(hnsh[i], w1[i * 128 + tid], m);
        mbsh[tid] = fmaxf(m, 0.f);
    }
    __syncthreads();

    // stage 5: MLP out + residual; tail (wave 0 only, no barriers needed)
    if (tid < 64) {
        float o = b2[tid];
        #pragma unroll 8
        for (int t = 0; t < 128; ++t) o = fmaf(mbsh[t], w2[t * 64 + tid], o);
        const float snv = hnsh[tid] + o;
        slots[r * 64 + tid] = snv;
        if (last) {
            out[r * 64 + tid] = snv;
        } else {
            const float mean = wsum(snv) * (1.0f / 64.0f);
            const float d = snv - mean;
            const float var = wsum(d * d) * (1.0f / 64.0f);
            const float rs = rsqrtf(var + 1e-5f);
            const float sn = d * rs * lsg[tid] + lsb[tid];
            ash[tid] = sn;                       // wave0-internal reuse
            float q = 0.f;
            #pragma unroll 8
            for (int i = 0; i < 64; ++i) q = fmaf(ash[i], Wq[i * 64 + tid], q);
            qsh[tid] = q * 0.125f;
            float kq = 0.f;
            #pragma unroll 8
            for (int p = 0; p < 64; ++p) kq = fmaf(WkT[p * 64 + tid], qsh[p], kq);
            const float bk = wsum(lib[tid] * kq);
            const float gk = lig[tid] * kq;
            const float g1 = wsum(gk);
            gkq[r * 64 + tid] = gk;
            if (tid == 0) { aux[r * 2] = g1; aux[r * 2 + 1] = bk; }
        }
    }
}

// ---------------------------------------------------------------------------
extern "C" void kernel_launch(void* const* d_in, const int* in_sizes, int n_in,
                              void* d_out, int out_size, void* d_ws, size_t ws_size,
                              hipStream_t stream)
{
    const float* x   = (const float*)d_in[0];
    const float* lig = (const float*)d_in[1];
    const float* lib = (const float*)d_in[2];
    const float* lsg = (const float*)d_in[3];
    const float* lsb = (const float*)d_in[4];
    const float* s0  = (const float*)d_in[5];
    const float* Wk  = (const float*)d_in[6];
    const float* Wv  = (const float*)d_in[7];
    const float* Wq  = (const float*)d_in[8];
    const float* wih = (const float*)d_in[9];
    const float* whh = (const float*)d_in[10];
    const float* bih = (const float*)d_in[11];
    const float* bhh = (const float*)d_in[12];
    const float* w1  = (const float*)d_in[13];
    const float* b1  = (const float*)d_in[14];
    const float* w2  = (const float*)d_in[15];
    const float* b2  = (const float*)d_in[16];

    float* f = (float*)d_ws;
    float* gkq   = f; f += 448 * 64;
    float* aux   = f; f += 448 * 2;
    float* slots = f; f += 448 * 64;
    float* Ypart = f; f += (long)64 * 16 * 456;
    float* wihT  = f; f += 64 * 192;
    float* whhT  = f; f += 64 * 192;
    float* WkT   = f; f += 64 * 64;

    init_kernel<<<112, 256, 0, stream>>>(s0, lsg, lsb, Wq, Wk, lig, lib,
                                         wih, whh, slots, gkq, aux,
                                         wihT, whhT, WkT);
    for (int it = 0; it < 3; ++it) {
        attn_kernel<<<1024, 256, 0, stream>>>(x, gkq, aux, Ypart);
        update_kernel<<<448, 256, 0, stream>>>(
            Ypart, slots, Wv, wihT, whhT, bih, bhh, w1, b1, w2, b2,
            lsg, lsb, Wq, WkT, lig, lib, gkq, aux,
            (float*)d_out, it == 2);
    }
}